// Round 7
// baseline (127.382 us; speedup 1.0000x reference)
//
#include <hip/hip_runtime.h>
#include <hip/hip_bf16.h>
#include <math.h>

#define B_ROWS 16384
#define NCOLS 32
#define EDIM 16
#define ACCD 512
#define NE 8
#define SBH 256
#define SBO 128
#define THD 16
#define NT 2

#define ROWS 32
#define THR 512

typedef __attribute__((ext_vector_type(8))) short bf16x8;
typedef __attribute__((ext_vector_type(4))) float f32x4;
typedef __attribute__((ext_vector_type(16))) float f32x16;

__device__ __forceinline__ short f2bf(float f) {
    unsigned u = __float_as_uint(f);
    unsigned r = (u + 0x7FFFu + ((u >> 16) & 1u)) >> 16;   // RNE
    return (short)r;
}

__device__ __forceinline__ bf16x8 pack8(float4 a, float4 b) {
    bf16x8 v;
    v[0] = f2bf(a.x); v[1] = f2bf(a.y); v[2] = f2bf(a.z); v[3] = f2bf(a.w);
    v[4] = f2bf(b.x); v[5] = f2bf(b.y); v[6] = f2bf(b.z); v[7] = f2bf(b.w);
    return v;
}

// ws: W1cF 256KB bf16 (32x32 frag-linear) | W2F 64KB bf16 (16x16 frag-linear) |
//     tw1T [32][128] bf16 | regparts int[768] | embB [500000][16] bf16 (16MB)
// W1cF frag (ks 0..31, cg 0..7): lane l -> col=cg*32+(l&31), k=ks*16+(l>>5)*8+j
// W2F  frag (ks 0..7,  cg 0..7): lane l -> col=cg*16+(l&15), k=ks*32+(l>>4)*8+j

#define CONV_BLOCKS 977
#define CONV_GROUPS 1000000   // 8e6 floats / 8

__global__ __launch_bounds__(256) void k_prep(const float* __restrict__ u1,
                                              const float* __restrict__ w1,
                                              const float* __restrict__ alpha1,
                                              const float* __restrict__ fce_w,
                                              const float* __restrict__ u2,
                                              const float* __restrict__ w2,
                                              const float* __restrict__ alpha2,
                                              const float* __restrict__ tw1,
                                              const float* __restrict__ emb,
                                              short* __restrict__ W1cF,
                                              short* __restrict__ W2F,
                                              short* __restrict__ tw1T,
                                              int* __restrict__ regparts,
                                              short* __restrict__ embB) {
    const int bid = blockIdx.x;
    const int tid = threadIdx.x;
    if (bid < 512) {
        const int a = bid, c = tid;         // a = k-index, c = col
        const float A = expf(-logf(alpha1[0]) * (1.0f / 0.9f));
        __shared__ int cnts[NE];
        if (c < NE) cnts[c] = 0;
        __syncthreads();
        float acc = 0.0f;
        #pragma unroll
        for (int n = 0; n < NE; ++n) {
            const int idx = (a * NE + n) * SBH + c;
            const float u = u1[idx];
            const float s = u / (u + (1.0f - u) * A);
            const float s_ = s * 2.1f - 0.1f;
            const float z = fminf(fmaxf(s_, 0.0f), 1.0f);
            acc += z * w1[idx] * fce_w[n];
            unsigned long long m = __ballot(s_ < 0.0f);
            if ((c & 63) == 0) atomicAdd(&cnts[n], __popcll(m));
        }
        __syncthreads();
        {
            const int ks = a >> 4, kr = a & 15;
            const int sub = kr >> 3, j = kr & 7;
            const int cg = c >> 5, lane = (sub << 5) | (c & 31);
            W1cF[(((ks * 8 + cg) * 64) + lane) * 8 + j] = f2bf(acc);
        }
        if (c == 0) {
            int tot = 0;
            #pragma unroll
            for (int n = 0; n < NE; ++n) tot += 1 - cnts[n] / NE;   // // NE (shape[1])
            regparts[a] = tot;
        }
    } else if (bid < 640) {
        const int c = (bid - 512) * 2 + (tid >> 7);   // k-index 0..255
        const int d = tid & 127;                      // col
        const float A = expf(-logf(alpha2[0]) * (1.0f / 0.9f));
        const int idx = c * SBO + d;
        const float u = u2[idx];
        const float s = u / (u + (1.0f - u) * A);
        const float s_ = s * 2.1f - 0.1f;
        const float z = fminf(fmaxf(s_, 0.0f), 1.0f);
        {
            const int ks = c >> 5, krem = c & 31;
            const int sub = krem >> 3, j = krem & 7;
            const int cg = d >> 4, lane = (sub << 4) | (d & 15);
            W2F[(((ks * 8 + cg) * 64) + lane) * 8 + j] = f2bf(z * w2[idx]);
        }
        __shared__ int cnts2[2];
        if (tid < 2) cnts2[tid] = 0;
        __syncthreads();
        unsigned long long m = __ballot(s_ < 0.0f);
        if ((tid & 63) == 0) atomicAdd(&cnts2[tid >> 7], __popcll(m));
        __syncthreads();
        if ((tid & 127) == 0) regparts[ACCD + c] = 1 - cnts2[tid >> 7] / SBO;  // // SBO
    } else if (bid == 640) {
        #pragma unroll
        for (int i = 0; i < 16; ++i) {
            const int e = tid * 16 + i;          // 4096 = 32*128
            const int jj = e >> 7;               // t*16+j
            const int d = e & 127;
            tw1T[jj * SBO + d] = f2bf(tw1[((jj >> 4) * SBO + d) * THD + (jj & 15)]);
        }
    } else {
        // stream-convert emb (fp32) -> embB (bf16); also re-warms L3 with embB
        const int base = (bid - 641) * 256 + tid;
        #pragma unroll
        for (int i = 0; i < 4; ++i) {
            const int g = base + i * (CONV_BLOCKS * 256);
            if (g < CONV_GROUPS) {
                const float4* sp = reinterpret_cast<const float4*>(emb + (size_t)g * 8);
                const float4 a = sp[0], b = sp[1];
                *reinterpret_cast<bf16x8*>(embB + (size_t)g * 8) = pack8(a, b);
            }
        }
    }
}

#define MFMA32(a, b, c) __builtin_amdgcn_mfma_f32_32x32x16_bf16((a), (b), (c), 0, 0, 0)
#define MFMA16(a, b, c) __builtin_amdgcn_mfma_f32_16x16x32_bf16((a), (b), (c), 0, 0, 0)

// LDS: A[32][512] bf16 @0 (32KB) | t[32][256] bf16 @32K (16KB) | o[32][128] bf16 @0 (aliases dead A)
#define LDS_T 32768

__global__ __launch_bounds__(THR, 6) void k_main(const int* __restrict__ x,
                                                 const short* __restrict__ embB,
                                                 const short* __restrict__ W1cF,
                                                 const short* __restrict__ W2F,
                                                 const short* __restrict__ tw1T,
                                                 const float* __restrict__ fce_b,
                                                 const float* __restrict__ tb1,
                                                 const float* __restrict__ tw2,
                                                 const float* __restrict__ tb2,
                                                 const int* __restrict__ regparts,
                                                 float* __restrict__ outp) {
    __shared__ __align__(16) char lds[49152];

    const int tid = threadIdx.x;
    const int l = tid & 63;
    const int w = tid >> 6;
    const int lrow32 = l & 31;
    const int hg = l >> 5;
    const int lrow16 = l & 15;
    const int lg4 = (l >> 4) & 3;
    const int rowbase = blockIdx.x * ROWS;

    // ---- stage A: each thread loads 2 bf16 emb rows (32B each), writes swizzled LDS ----
    {
        const int srow = tid >> 4;           // 0..31
        const int scol = tid & 15;           // 0..15
        char* sbase = lds + (srow << 10);
        const int sswz = (srow & 15) << 4;
        const int xv0 = x[(rowbase + srow) * NCOLS + scol];
        const int xv1 = x[(rowbase + srow) * NCOLS + 16 + scol];
        const bf16x8* r0 = reinterpret_cast<const bf16x8*>(embB + (size_t)xv0 * EDIM);
        const bf16x8* r1 = reinterpret_cast<const bf16x8*>(embB + (size_t)xv1 * EDIM);
        const bf16x8 v00 = r0[0], v01 = r0[1];
        const bf16x8 v10 = r1[0], v11 = r1[1];
        *(bf16x8*)(sbase + ((scol * 32 + 0) ^ sswz))  = v00;
        *(bf16x8*)(sbase + ((scol * 32 + 16) ^ sswz)) = v01;
        *(bf16x8*)(sbase + (((16 + scol) * 32 + 0) ^ sswz))  = v10;
        *(bf16x8*)(sbase + (((16 + scol) * 32 + 16) ^ sswz)) = v11;
    }
    __syncthreads();

    // ---- GEMM1: t[32][256] = xf[32][512] x W1c[512][256]; wave w -> cols w*32..+31 ----
    char* aAb = lds + (lrow32 << 10);
    const int aswz = (lrow32 & 15) << 4;
    const bf16x8* Bp = ((const bf16x8*)W1cF) + l;

    f32x16 acc;
    #pragma unroll
    for (int i = 0; i < 16; ++i) acc[i] = 0.0f;

    bf16x8 b0 = Bp[(0 * 8 + w) * 64];
    bf16x8 b1 = Bp[(1 * 8 + w) * 64];
    bf16x8 b2 = Bp[(2 * 8 + w) * 64];
    bf16x8 b3 = Bp[(3 * 8 + w) * 64];

    #pragma unroll
    for (int ks = 0; ks < 32; ks += 4) {
        { const bf16x8 a = *(const bf16x8*)(aAb + ((((ks + 0) * 32) + hg * 16) ^ aswz));
          acc = MFMA32(a, b0, acc); if (ks + 4 < 32) b0 = Bp[((ks + 4) * 8 + w) * 64]; }
        { const bf16x8 a = *(const bf16x8*)(aAb + ((((ks + 1) * 32) + hg * 16) ^ aswz));
          acc = MFMA32(a, b1, acc); if (ks + 5 < 32) b1 = Bp[((ks + 5) * 8 + w) * 64]; }
        { const bf16x8 a = *(const bf16x8*)(aAb + ((((ks + 2) * 32) + hg * 16) ^ aswz));
          acc = MFMA32(a, b2, acc); if (ks + 6 < 32) b2 = Bp[((ks + 6) * 8 + w) * 64]; }
        { const bf16x8 a = *(const bf16x8*)(aAb + ((((ks + 3) * 32) + hg * 16) ^ aswz));
          acc = MFMA32(a, b3, acc); if (ks + 7 < 32) b3 = Bp[((ks + 7) * 8 + w) * 64]; }
    }

    // ---- GEMM2 B prefetch (issued before t-barrier) ----
    const int cgA = (w & 3) * 2;
    const int rg2 = w >> 2;
    const bf16x8* Bp2 = ((const bf16x8*)W2F) + l;
    bf16x8 q0a = Bp2[(0 * 8 + cgA) * 64], q0b = Bp2[(0 * 8 + cgA + 1) * 64];
    bf16x8 q1a = Bp2[(1 * 8 + cgA) * 64], q1b = Bp2[(1 * 8 + cgA + 1) * 64];

    // ---- t write (bf16 swizzled). D(32x32): col=l&31, row=(r&3)+8*(r>>2)+4*hg ----
    {
        const int tcol2 = (w * 32 + lrow32) * 2;
        #pragma unroll
        for (int r = 0; r < 16; ++r) {
            const int trow = (r & 3) + 8 * (r >> 2) + 4 * hg;
            *(short*)(lds + LDS_T + (trow << 9) + (tcol2 ^ ((trow & 15) << 4))) = f2bf(acc[r]);
        }
    }
    __syncthreads();

    // ---- GEMM2: o[32][128] = t[32][256] x W2eff[256][128]; wave: rows rg2*16, cols cgA*16..+31 ----
    f32x4 acc2[2];
    acc2[0] = (f32x4){0.f, 0.f, 0.f, 0.f};
    acc2[1] = (f32x4){0.f, 0.f, 0.f, 0.f};
    {
        char* tAb = lds + LDS_T + ((rg2 * 16 + lrow16) << 9);
        const int tswz = (lrow16 & 15) << 4;
        #pragma unroll
        for (int kc = 0; kc < 8; kc += 2) {
            { const bf16x8 a = *(const bf16x8*)(tAb + ((((kc + 0) * 64) + lg4 * 16) ^ tswz));
              acc2[0] = MFMA16(a, q0a, acc2[0]);
              acc2[1] = MFMA16(a, q0b, acc2[1]);
              if (kc + 2 < 8) { q0a = Bp2[((kc + 2) * 8 + cgA) * 64]; q0b = Bp2[((kc + 2) * 8 + cgA + 1) * 64]; } }
            { const bf16x8 a = *(const bf16x8*)(tAb + ((((kc + 1) * 64) + lg4 * 16) ^ tswz));
              acc2[0] = MFMA16(a, q1a, acc2[0]);
              acc2[1] = MFMA16(a, q1b, acc2[1]);
              if (kc + 3 < 8) { q1a = Bp2[((kc + 3) * 8 + cgA) * 64]; q1b = Bp2[((kc + 3) * 8 + cgA + 1) * 64]; } }
        }
    }

    // ---- o write (relu + fce_b) into [0,8K): aliases dead A region. D(16x16): col=l&15, row=lg4*4+r ----
    {
        const float fb = fce_b[0];
        #pragma unroll
        for (int fd = 0; fd < 2; ++fd) {
            const int d2 = ((cgA + fd) * 16 + lrow16) * 2;
            #pragma unroll
            for (int rr = 0; rr < 4; ++rr) {
                const int orow = rg2 * 16 + lg4 * 4 + rr;
                *(short*)(lds + (orow << 8) + (d2 ^ ((orow & 15) << 4))) =
                    f2bf(fmaxf(acc2[fd][rr] + fb, 0.0f));
            }
        }
    }
    __syncthreads();

    // ---- towers: waves 0..3: rows (w>>1)*16..+15, task w&1 ----
    if (w < 4) {
        const int rtt = w >> 1, ct = w & 1;
        f32x4 h = (f32x4){0.f, 0.f, 0.f, 0.f};
        char* oAb = lds + ((rtt * 16 + lrow16) << 8);
        const int oswz = (lrow16 & 15) << 4;
        const short* bT = tw1T + (ct * 16 + lrow16) * SBO + lg4 * 8;
        #pragma unroll
        for (int kc = 0; kc < 4; ++kc) {
            const bf16x8 av = *(const bf16x8*)(oAb + ((kc * 64 + lg4 * 16) ^ oswz));
            const bf16x8 bv = *(const bf16x8*)(bT + kc * 32);
            h = MFMA16(av, bv, h);
        }
        const float b1v = tb1[ct * THD + lrow16];
        const float w2v = tw2[ct * THD + lrow16];
        float p[4];
        #pragma unroll
        for (int rr = 0; rr < 4; ++rr) {
            p[rr] = fmaxf(h[rr] + b1v, 0.0f) * w2v;
            #pragma unroll
            for (int off = 8; off >= 1; off >>= 1)
                p[rr] += __shfl_xor(p[rr], off);
        }
        if (lrow16 == 0) {
            const float b2v = tb2[ct];
            #pragma unroll
            for (int rr = 0; rr < 4; ++rr) {
                const int rowo = rtt * 16 + lg4 * 4 + rr;
                outp[ct * B_ROWS + rowbase + rowo] = 1.0f / (1.0f + __expf(-(p[rr] + b2v)));
            }
        }
    }

    // ---- regularizer (block 0) ----
    if (blockIdx.x == 0 && tid < 64) {
        int s = 0;
        for (int i = tid; i < ACCD + SBH; i += 64) s += regparts[i];
        #pragma unroll
        for (int off = 32; off > 0; off >>= 1) s += __shfl_down(s, off);
        if (tid == 0) outp[NT * B_ROWS] = 1e-4f * (float)s;
    }
}

extern "C" void kernel_launch(void* const* d_in, const int* in_sizes, int n_in,
                              void* d_out, int out_size, void* d_ws, size_t ws_size,
                              hipStream_t stream) {
    const int*   x      = (const int*)d_in[0];
    const float* emb    = (const float*)d_in[1];
    const float* alpha1 = (const float*)d_in[2];
    const float* u1     = (const float*)d_in[3];
    const float* w1     = (const float*)d_in[4];
    const float* alpha2 = (const float*)d_in[5];
    const float* u2     = (const float*)d_in[6];
    const float* w2     = (const float*)d_in[7];
    const float* fce_w  = (const float*)d_in[8];
    const float* fce_b  = (const float*)d_in[9];
    const float* tw1    = (const float*)d_in[10];
    const float* tb1    = (const float*)d_in[11];
    const float* tw2    = (const float*)d_in[12];
    const float* tb2    = (const float*)d_in[13];
    float* outp = (float*)d_out;

    short* W1cF = (short*)d_ws;                       // 131072 shorts
    short* W2F  = W1cF + 32 * 8 * 64 * 8;             // 32768 shorts
    short* tw1T = W2F + 8 * 8 * 64 * 8;               // 4096 shorts
    int*   regparts = (int*)(tw1T + NT * THD * SBO);  // 768 ints
    short* embB = (short*)(regparts + 768);           // 8e6 shorts (16 MB)

    k_prep<<<641 + CONV_BLOCKS, 256, 0, stream>>>(u1, w1, alpha1, fce_w, u2, w2,
                                                  alpha2, tw1, emb,
                                                  W1cF, W2F, tw1T, regparts, embB);
    k_main<<<B_ROWS / ROWS, THR, 0, stream>>>(x, embB, W1cF, W2F, tw1T, fce_b,
                                              tb1, tw2, tb2, regparts, outp);
}

// Round 8
// 126.464 us; speedup vs baseline: 1.0073x; 1.0073x over previous
//
#include <hip/hip_runtime.h>
#include <hip/hip_bf16.h>
#include <math.h>

#define B_ROWS 16384
#define NCOLS 32
#define EDIM 16
#define ACCD 512
#define NE 8
#define SBH 256
#define SBO 128
#define THD 16
#define NT 2

#define ROWS 32
#define THR 512

typedef __attribute__((ext_vector_type(8))) short bf16x8;
typedef __attribute__((ext_vector_type(4))) float f32x4;
typedef __attribute__((ext_vector_type(16))) float f32x16;

__device__ __forceinline__ short f2bf(float f) {
    unsigned u = __float_as_uint(f);
    unsigned r = (u + 0x7FFFu + ((u >> 16) & 1u)) >> 16;   // RNE
    return (short)r;
}

__device__ __forceinline__ bf16x8 pack8(float4 a, float4 b) {
    bf16x8 v;
    v[0] = f2bf(a.x); v[1] = f2bf(a.y); v[2] = f2bf(a.z); v[3] = f2bf(a.w);
    v[4] = f2bf(b.x); v[5] = f2bf(b.y); v[6] = f2bf(b.z); v[7] = f2bf(b.w);
    return v;
}

// ws: W1cF 256KB bf16 (32x32 frag-linear) | W2F 64KB bf16 (16x16 frag-linear) |
//     tw1T [32][128] bf16 | regparts int[768]
// W1cF frag (ks 0..31, cg 0..7): lane l -> col=cg*32+(l&31), k=ks*16+(l>>5)*8+j
// W2F  frag (ks 0..7,  cg 0..7): lane l -> col=cg*16+(l&15), k=ks*32+(l>>4)*8+j

#define SWEEP_BLOCKS 512
#define SWEEP_F4 2000000   // 8e6 floats / 4

__global__ __launch_bounds__(256) void k_prep(const float* __restrict__ u1,
                                              const float* __restrict__ w1,
                                              const float* __restrict__ alpha1,
                                              const float* __restrict__ fce_w,
                                              const float* __restrict__ u2,
                                              const float* __restrict__ w2,
                                              const float* __restrict__ alpha2,
                                              const float* __restrict__ tw1,
                                              const float* __restrict__ emb,
                                              short* __restrict__ W1cF,
                                              short* __restrict__ W2F,
                                              short* __restrict__ tw1T,
                                              int* __restrict__ regparts) {
    const int bid = blockIdx.x;
    const int tid = threadIdx.x;
    if (bid < 512) {
        const int a = bid, c = tid;         // a = k-index, c = col
        const float A = expf(-logf(alpha1[0]) * (1.0f / 0.9f));
        __shared__ int cnts[NE];
        if (c < NE) cnts[c] = 0;
        __syncthreads();
        float acc = 0.0f;
        #pragma unroll
        for (int n = 0; n < NE; ++n) {
            const int idx = (a * NE + n) * SBH + c;
            const float u = u1[idx];
            const float s = u / (u + (1.0f - u) * A);
            const float s_ = s * 2.1f - 0.1f;
            const float z = fminf(fmaxf(s_, 0.0f), 1.0f);
            acc += z * w1[idx] * fce_w[n];
            unsigned long long m = __ballot(s_ < 0.0f);
            if ((c & 63) == 0) atomicAdd(&cnts[n], __popcll(m));
        }
        __syncthreads();
        {
            const int ks = a >> 4, kr = a & 15;
            const int sub = kr >> 3, j = kr & 7;
            const int cg = c >> 5, lane = (sub << 5) | (c & 31);
            W1cF[(((ks * 8 + cg) * 64) + lane) * 8 + j] = f2bf(acc);
        }
        if (c == 0) {
            int tot = 0;
            #pragma unroll
            for (int n = 0; n < NE; ++n) tot += 1 - cnts[n] / NE;   // // NE (shape[1])
            regparts[a] = tot;
        }
    } else if (bid < 640) {
        const int c = (bid - 512) * 2 + (tid >> 7);   // k-index 0..255
        const int d = tid & 127;                      // col
        const float A = expf(-logf(alpha2[0]) * (1.0f / 0.9f));
        const int idx = c * SBO + d;
        const float u = u2[idx];
        const float s = u / (u + (1.0f - u) * A);
        const float s_ = s * 2.1f - 0.1f;
        const float z = fminf(fmaxf(s_, 0.0f), 1.0f);
        {
            const int ks = c >> 5, krem = c & 31;
            const int sub = krem >> 3, j = krem & 7;
            const int cg = d >> 4, lane = (sub << 4) | (d & 15);
            W2F[(((ks * 8 + cg) * 64) + lane) * 8 + j] = f2bf(z * w2[idx]);
        }
        __shared__ int cnts2[2];
        if (tid < 2) cnts2[tid] = 0;
        __syncthreads();
        unsigned long long m = __ballot(s_ < 0.0f);
        if ((tid & 63) == 0) atomicAdd(&cnts2[tid >> 7], __popcll(m));
        __syncthreads();
        if ((tid & 127) == 0) regparts[ACCD + c] = 1 - cnts2[tid >> 7] / SBO;  // // SBO
    } else if (bid == 640) {
        #pragma unroll
        for (int i = 0; i < 16; ++i) {
            const int e = tid * 16 + i;          // 4096 = 32*128
            const int jj = e >> 7;               // t*16+j
            const int d = e & 127;
            tw1T[jj * SBO + d] = f2bf(tw1[((jj >> 4) * SBO + d) * THD + (jj & 15)]);
        }
    } else {
        // L3 warm sweep: sequential read of all of emb; kept alive, no stores.
        const int idx = (bid - 641) * 256 + tid;
        float accw = 0.0f;
        #pragma unroll
        for (int i = 0; i < 16; ++i) {
            const int g = idx + i * (SWEEP_BLOCKS * 256);
            if (g < SWEEP_F4) {
                const float4 v = reinterpret_cast<const float4*>(emb)[g];
                accw += v.x + v.y + v.z + v.w;
            }
        }
        asm volatile("" :: "v"(accw));   // keep loads live without a store (rule 17)
    }
}

#define MFMA32(a, b, c) __builtin_amdgcn_mfma_f32_32x32x16_bf16((a), (b), (c), 0, 0, 0)
#define MFMA16(a, b, c) __builtin_amdgcn_mfma_f32_16x16x32_bf16((a), (b), (c), 0, 0, 0)

// LDS: A[32][512] bf16 @0 (32KB) | t[32][256] bf16 @32K (16KB) | o[32][128] bf16 @0 (aliases dead A)
#define LDS_T 32768

__global__ __launch_bounds__(THR, 4) void k_main(const int* __restrict__ x,
                                                 const float* __restrict__ emb,
                                                 const short* __restrict__ W1cF,
                                                 const short* __restrict__ W2F,
                                                 const short* __restrict__ tw1T,
                                                 const float* __restrict__ fce_b,
                                                 const float* __restrict__ tb1,
                                                 const float* __restrict__ tw2,
                                                 const float* __restrict__ tb2,
                                                 const int* __restrict__ regparts,
                                                 float* __restrict__ outp) {
    __shared__ __align__(16) char lds[49152];

    const int tid = threadIdx.x;
    const int l = tid & 63;
    const int w = tid >> 6;
    const int lrow32 = l & 31;
    const int hg = l >> 5;
    const int lrow16 = l & 15;
    const int lg4 = (l >> 4) & 3;
    const int rowbase = blockIdx.x * ROWS;

    // ---- stage A: each thread gathers 2 emb rows (64B fp32 each), converts, swizzled LDS ----
    {
        const int srow = tid >> 4;           // 0..31
        const int scol = tid & 15;           // 0..15
        char* sbase = lds + (srow << 10);
        const int sswz = (srow & 15) << 4;
        const int xv0 = x[(rowbase + srow) * NCOLS + scol];
        const int xv1 = x[(rowbase + srow) * NCOLS + 16 + scol];
        const float4* r0 = reinterpret_cast<const float4*>(emb + (size_t)xv0 * EDIM);
        const float4* r1 = reinterpret_cast<const float4*>(emb + (size_t)xv1 * EDIM);
        const float4 e0 = r0[0], e1 = r0[1], e2 = r0[2], e3 = r0[3];
        const float4 f0 = r1[0], f1 = r1[1], f2 = r1[2], f3 = r1[3];
        *(bf16x8*)(sbase + ((scol * 32 + 0) ^ sswz))  = pack8(e0, e1);
        *(bf16x8*)(sbase + ((scol * 32 + 16) ^ sswz)) = pack8(e2, e3);
        *(bf16x8*)(sbase + (((16 + scol) * 32 + 0) ^ sswz))  = pack8(f0, f1);
        *(bf16x8*)(sbase + (((16 + scol) * 32 + 16) ^ sswz)) = pack8(f2, f3);
    }
    __syncthreads();

    // ---- GEMM1: t[32][256] = xf[32][512] x W1c[512][256]; wave w -> cols w*32..+31 ----
    char* aAb = lds + (lrow32 << 10);
    const int aswz = (lrow32 & 15) << 4;
    const bf16x8* Bp = ((const bf16x8*)W1cF) + l;

    f32x16 acc;
    #pragma unroll
    for (int i = 0; i < 16; ++i) acc[i] = 0.0f;

    bf16x8 b0 = Bp[(0 * 8 + w) * 64];
    bf16x8 b1 = Bp[(1 * 8 + w) * 64];
    bf16x8 b2 = Bp[(2 * 8 + w) * 64];
    bf16x8 b3 = Bp[(3 * 8 + w) * 64];

    #pragma unroll
    for (int ks = 0; ks < 32; ks += 4) {
        { const bf16x8 a = *(const bf16x8*)(aAb + ((((ks + 0) * 32) + hg * 16) ^ aswz));
          acc = MFMA32(a, b0, acc); if (ks + 4 < 32) b0 = Bp[((ks + 4) * 8 + w) * 64]; }
        { const bf16x8 a = *(const bf16x8*)(aAb + ((((ks + 1) * 32) + hg * 16) ^ aswz));
          acc = MFMA32(a, b1, acc); if (ks + 5 < 32) b1 = Bp[((ks + 5) * 8 + w) * 64]; }
        { const bf16x8 a = *(const bf16x8*)(aAb + ((((ks + 2) * 32) + hg * 16) ^ aswz));
          acc = MFMA32(a, b2, acc); if (ks + 6 < 32) b2 = Bp[((ks + 6) * 8 + w) * 64]; }
        { const bf16x8 a = *(const bf16x8*)(aAb + ((((ks + 3) * 32) + hg * 16) ^ aswz));
          acc = MFMA32(a, b3, acc); if (ks + 7 < 32) b3 = Bp[((ks + 7) * 8 + w) * 64]; }
    }

    // ---- GEMM2 B prefetch (issued before t-barrier) ----
    const int cgA = (w & 3) * 2;
    const int rg2 = w >> 2;
    const bf16x8* Bp2 = ((const bf16x8*)W2F) + l;
    bf16x8 q0a = Bp2[(0 * 8 + cgA) * 64], q0b = Bp2[(0 * 8 + cgA + 1) * 64];
    bf16x8 q1a = Bp2[(1 * 8 + cgA) * 64], q1b = Bp2[(1 * 8 + cgA + 1) * 64];

    // ---- t write (bf16 swizzled). D(32x32): col=l&31, row=(r&3)+8*(r>>2)+4*hg ----
    {
        const int tcol2 = (w * 32 + lrow32) * 2;
        #pragma unroll
        for (int r = 0; r < 16; ++r) {
            const int trow = (r & 3) + 8 * (r >> 2) + 4 * hg;
            *(short*)(lds + LDS_T + (trow << 9) + (tcol2 ^ ((trow & 15) << 4))) = f2bf(acc[r]);
        }
    }
    __syncthreads();

    // ---- GEMM2: o[32][128] = t[32][256] x W2eff[256][128]; wave: rows rg2*16, cols cgA*16..+31 ----
    f32x4 acc2[2];
    acc2[0] = (f32x4){0.f, 0.f, 0.f, 0.f};
    acc2[1] = (f32x4){0.f, 0.f, 0.f, 0.f};
    {
        char* tAb = lds + LDS_T + ((rg2 * 16 + lrow16) << 9);
        const int tswz = (lrow16 & 15) << 4;
        #pragma unroll
        for (int kc = 0; kc < 8; kc += 2) {
            { const bf16x8 a = *(const bf16x8*)(tAb + ((((kc + 0) * 64) + lg4 * 16) ^ tswz));
              acc2[0] = MFMA16(a, q0a, acc2[0]);
              acc2[1] = MFMA16(a, q0b, acc2[1]);
              if (kc + 2 < 8) { q0a = Bp2[((kc + 2) * 8 + cgA) * 64]; q0b = Bp2[((kc + 2) * 8 + cgA + 1) * 64]; } }
            { const bf16x8 a = *(const bf16x8*)(tAb + ((((kc + 1) * 64) + lg4 * 16) ^ tswz));
              acc2[0] = MFMA16(a, q1a, acc2[0]);
              acc2[1] = MFMA16(a, q1b, acc2[1]);
              if (kc + 3 < 8) { q1a = Bp2[((kc + 3) * 8 + cgA) * 64]; q1b = Bp2[((kc + 3) * 8 + cgA + 1) * 64]; } }
        }
    }

    // ---- o write (relu + fce_b) into [0,8K): aliases dead A region. D(16x16): col=l&15, row=lg4*4+r ----
    {
        const float fb = fce_b[0];
        #pragma unroll
        for (int fd = 0; fd < 2; ++fd) {
            const int d2 = ((cgA + fd) * 16 + lrow16) * 2;
            #pragma unroll
            for (int rr = 0; rr < 4; ++rr) {
                const int orow = rg2 * 16 + lg4 * 4 + rr;
                *(short*)(lds + (orow << 8) + (d2 ^ ((orow & 15) << 4))) =
                    f2bf(fmaxf(acc2[fd][rr] + fb, 0.0f));
            }
        }
    }
    __syncthreads();

    // ---- towers: waves 0..3: rows (w>>1)*16..+15, task w&1 ----
    if (w < 4) {
        const int rtt = w >> 1, ct = w & 1;
        f32x4 h = (f32x4){0.f, 0.f, 0.f, 0.f};
        char* oAb = lds + ((rtt * 16 + lrow16) << 8);
        const int oswz = (lrow16 & 15) << 4;
        const short* bT = tw1T + (ct * 16 + lrow16) * SBO + lg4 * 8;
        #pragma unroll
        for (int kc = 0; kc < 4; ++kc) {
            const bf16x8 av = *(const bf16x8*)(oAb + ((kc * 64 + lg4 * 16) ^ oswz));
            const bf16x8 bv = *(const bf16x8*)(bT + kc * 32);
            h = MFMA16(av, bv, h);
        }
        const float b1v = tb1[ct * THD + lrow16];
        const float w2v = tw2[ct * THD + lrow16];
        float p[4];
        #pragma unroll
        for (int rr = 0; rr < 4; ++rr) {
            p[rr] = fmaxf(h[rr] + b1v, 0.0f) * w2v;
            #pragma unroll
            for (int off = 8; off >= 1; off >>= 1)
                p[rr] += __shfl_xor(p[rr], off);
        }
        if (lrow16 == 0) {
            const float b2v = tb2[ct];
            #pragma unroll
            for (int rr = 0; rr < 4; ++rr) {
                const int rowo = rtt * 16 + lg4 * 4 + rr;
                outp[ct * B_ROWS + rowbase + rowo] = 1.0f / (1.0f + __expf(-(p[rr] + b2v)));
            }
        }
    }

    // ---- regularizer (block 0) ----
    if (blockIdx.x == 0 && tid < 64) {
        int s = 0;
        for (int i = tid; i < ACCD + SBH; i += 64) s += regparts[i];
        #pragma unroll
        for (int off = 32; off > 0; off >>= 1) s += __shfl_down(s, off);
        if (tid == 0) outp[NT * B_ROWS] = 1e-4f * (float)s;
    }
}

extern "C" void kernel_launch(void* const* d_in, const int* in_sizes, int n_in,
                              void* d_out, int out_size, void* d_ws, size_t ws_size,
                              hipStream_t stream) {
    const int*   x      = (const int*)d_in[0];
    const float* emb    = (const float*)d_in[1];
    const float* alpha1 = (const float*)d_in[2];
    const float* u1     = (const float*)d_in[3];
    const float* w1     = (const float*)d_in[4];
    const float* alpha2 = (const float*)d_in[5];
    const float* u2     = (const float*)d_in[6];
    const float* w2     = (const float*)d_in[7];
    const float* fce_w  = (const float*)d_in[8];
    const float* fce_b  = (const float*)d_in[9];
    const float* tw1    = (const float*)d_in[10];
    const float* tb1    = (const float*)d_in[11];
    const float* tw2    = (const float*)d_in[12];
    const float* tb2    = (const float*)d_in[13];
    float* outp = (float*)d_out;

    short* W1cF = (short*)d_ws;                       // 131072 shorts
    short* W2F  = W1cF + 32 * 8 * 64 * 8;             // 32768 shorts
    short* tw1T = W2F + 8 * 8 * 64 * 8;               // 4096 shorts
    int*   regparts = (int*)(tw1T + NT * THD * SBO);  // 768 ints

    k_prep<<<641 + SWEEP_BLOCKS, 256, 0, stream>>>(u1, w1, alpha1, fce_w, u2, w2,
                                                   alpha2, tw1, emb,
                                                   W1cF, W2F, tw1T, regparts);
    k_main<<<B_ROWS / ROWS, THR, 0, stream>>>(x, emb, W1cF, W2F, tw1T, fce_b,
                                              tb1, tw2, tb2, regparts, outp);
}